// Round 5
// baseline (534.280 us; speedup 1.0000x reference)
//
#include <hip/hip_runtime.h>
#include <cstddef>

// DynamicNetwork via split-bf16 MFMA (hi/lo, 3 MFMA per product).
// R5: LDS-free GEMM. One wave per 64x64 tile; MFMA fragments loaded directly
// from global (L2-resident via XCD swizzle); each element read once per block.
// All row strides padded to 64B. No barriers in the GEMM at all.

typedef short short8 __attribute__((ext_vector_type(8)));
typedef float floatx16 __attribute__((ext_vector_type(16)));

#define EMB_BLOCKS 832
// padded strides (elements)
#define SN0 224   // node0 k-stride (208 used)
#define SN1 448   // node1 k-stride (416 used)
#define SH  416   // hidden/node k-stride (400 used)

__device__ __forceinline__ unsigned short f2bf(float f) {
    unsigned int u = __float_as_uint(f);
    u += 0x7fffu + ((u >> 16) & 1u);
    return (unsigned short)(u >> 16);
}
__device__ __forceinline__ float bf2f(unsigned short h) {
    return __uint_as_float((unsigned int)h << 16);
}
__device__ __forceinline__ void split2(float v, unsigned short& h, unsigned short& l) {
    h = f2bf(v);
    l = f2bf(v - bf2f(h));
}

// ---------------- prep1: column sums + alpha scalars ----------------
__global__ __launch_bounds__(256) void prep1_kernel(
    const float* __restrict__ Pd, const float* __restrict__ Ps, const float* __restrict__ Pb,
    const float* __restrict__ a0, const float* __restrict__ a1,
    const float* __restrict__ a2, const float* __restrict__ a3,
    float* __restrict__ scal,
    float* __restrict__ csd, float* __restrict__ css, float* __restrict__ csb)
{
    int gid = blockIdx.x * 256 + threadIdx.x;
    if (gid < 400) {
        float s = 0.f;
        for (int k = 0; k < 208; ++k) s += Pd[k*400 + gid];
        csd[gid] = s;
    } else if (gid < 800) {
        int j = gid - 400; float s = 0.f;
        for (int k = 0; k < 416; ++k) s += Ps[k*400 + j];
        css[j] = s;
    } else if (gid < 1200) {
        int j = gid - 800; float s = 0.f;
        for (int k = 0; k < 400; ++k) s += Pb[k*400 + j];
        csb[j] = s;
    } else if (gid < 1204) {
        int i = gid - 1200;
        const float* a = (i==0) ? a0 : (i==1) ? a1 : (i==2) ? a2 : a3;
        int np = 2 + i;
        float sum1 = 0.f, sum2 = 0.f, sumc = 0.f;
        for (int j = 0; j < np; ++j) { sum1 += a[j]; sum2 += a[np+j]; }
        for (int j = 0; j < 4; ++j) sumc += a[2*np+j];
        int i1 = (i==0) ? 0 : 1;
        int i2 = i + 1;
        int kk = i;
        float s1 = a[i1],      c1 = sum1 - s1;
        float s2 = a[np+i2],   c2 = sum2 - s2;
        float sk = a[2*np+kk], ck = sumc - sk;
        float* sl = scal + i*8;
        if (i == 0) { sl[0]=s1; sl[1]=c1; sl[2]=s2; sl[3]=c2; }
        else        { sl[0]=s2; sl[1]=c2; sl[2]=s1; sl[3]=c1; }
        sl[4] = sk; sl[5] = ck;
    }
}

// ---------------- prep2: transpose + scale + split weights -> [448][Kw] bf16 hi|lo planes
__global__ __launch_bounds__(256) void prep2_kernel(
    const float* __restrict__ Pd, const float* __restrict__ Ps,
    const float* __restrict__ Pb, const float* __restrict__ Wc,
    const float* __restrict__ scal,
    unsigned short* __restrict__ w0, unsigned short* __restrict__ w1,
    unsigned short* __restrict__ w2, unsigned short* __restrict__ w3,
    unsigned short* __restrict__ v0, unsigned short* __restrict__ v1,
    unsigned short* __restrict__ v2, unsigned short* __restrict__ v3)
{
    int z = blockIdx.z;
    int Kp, KA, Kw; const float *sA, *sB; float sc1, sc2; unsigned short* dst;
    if (z < 4) {
        Kp = (z==0) ? 624 : 816; KA = (z==0) ? 208 : 400; Kw = (z==0) ? 640 : 832;
        sA = (z==0) ? Pd : Pb; sB = Ps;
        sc1 = scal[z*8+0]; sc2 = scal[z*8+2];
        dst = (z==0) ? w0 : (z==1) ? w1 : (z==2) ? w2 : w3;
    } else {
        int i = z - 4;
        Kp = 400; KA = 400; Kw = 416;
        sA = Wc + (size_t)i*5*160000; sB = nullptr;
        sc1 = scal[i*8+4]; sc2 = 0.f;
        dst = (i==0) ? v0 : (i==1) ? v1 : (i==2) ? v2 : v3;
    }
    int ktiles = (Kp + 63) >> 6;
    if ((int)blockIdx.y >= ktiles) return;
    int k0 = blockIdx.y * 64, n0 = blockIdx.x * 64;
    __shared__ float T[64][65];
    int t = threadIdx.x;
    {
        int kr = t >> 2, c0 = (t & 3) * 16;
        int gk = k0 + kr;
        bool kok = gk < Kp;
        const float* src; int srow; float sc;
        if (gk < KA) { src = sA; srow = gk; sc = sc1; }
        else         { src = sB; srow = gk - KA; sc = sc2; }
        for (int j = 0; j < 16; j += 4) {
            int n = n0 + c0 + j;
            float4 v = make_float4(0.f,0.f,0.f,0.f);
            if (kok && n < 400) v = *(const float4*)&src[(size_t)srow*400 + n];
            T[kr][c0+j+0] = v.x * sc;
            T[kr][c0+j+1] = v.y * sc;
            T[kr][c0+j+2] = v.z * sc;
            T[kr][c0+j+3] = v.w * sc;
        }
    }
    __syncthreads();
    {
        int nr = t >> 2, kc0 = (t & 3) * 16;
        int gn = n0 + nr;
        int gk0 = k0 + kc0;
        if (gk0 >= Kp) return;
        unsigned short hb[16], lb[16];
        for (int j = 0; j < 16; ++j) {
            float v = (gn < 400) ? T[kc0+j][nr] : 0.f;
            split2(v, hb[j], lb[j]);
        }
        unsigned short* dh = dst + (size_t)gn*Kw + gk0;
        unsigned short* dl = dst + (size_t)448*Kw + (size_t)gn*Kw + gk0;
        *(uint4*)&dh[0] = *(uint4*)&hb[0]; *(uint4*)&dh[8] = *(uint4*)&hb[8];
        *(uint4*)&dl[0] = *(uint4*)&lb[0]; *(uint4*)&dl[8] = *(uint4*)&lb[8];
    }
}

// ---------------- prep3: epilogue vectors cvec/dvec ----------------
__global__ __launch_bounds__(256) void prep3_kernel(
    const float* __restrict__ scal,
    const float* __restrict__ csd, const float* __restrict__ css, const float* __restrict__ csb,
    const float* __restrict__ bc,
    float* __restrict__ cv, float* __restrict__ dv)
{
    int i = blockIdx.x;
    for (int j = threadIdx.x; j < 448; j += 256) {
        float c = 0.f, d = 0.f;
        if (j < 400) {
            const float* cs1 = (i==0) ? csd : csb;
            c = scal[i*8+1]*cs1[j] + scal[i*8+3]*css[j];
            d = scal[i*8+4]*bc[i*5*400 + j] + scal[i*8+5];
        }
        cv[i*448 + j] = c;
        dv[i*448 + j] = d;
    }
}

// ---------------- embed: node0/node1 bf16 hi/lo planes (padded strides) ----------------
__global__ __launch_bounds__(256) void embed_kernel(
    const float* __restrict__ rd, const int* __restrict__ rs,
    const float* __restrict__ emb,
    unsigned short* __restrict__ n0h, unsigned short* __restrict__ n0l,
    unsigned short* __restrict__ n1h, unsigned short* __restrict__ n1l,
    float* __restrict__ partial)
{
    int tid0 = blockIdx.x*256 + threadIdx.x;
    int nth = gridDim.x*256;
    float ssq = 0.f, dsq = 0.f;
    for (int it = tid0; it < 8192*26; it += nth) {
        int b = it / 26, s = it - b*26;
        int row = 13 + 50000*s + rs[b*26 + s];
        const float* e = emb + (size_t)row*16;
        float4 e0 = *(const float4*)&e[0], e1 = *(const float4*)&e[4];
        float4 e2 = *(const float4*)&e[8], e3 = *(const float4*)&e[12];
        float vv[16] = {e0.x,e0.y,e0.z,e0.w, e1.x,e1.y,e1.z,e1.w,
                        e2.x,e2.y,e2.z,e2.w, e3.x,e3.y,e3.z,e3.w};
        unsigned short hb[16], lb[16];
        for (int j = 0; j < 16; ++j) { ssq += vv[j]*vv[j]; split2(vv[j], hb[j], lb[j]); }
        size_t off = (size_t)b*SN1 + s*16;
        *(uint4*)&n1h[off] = *(uint4*)&hb[0]; *(uint4*)&n1h[off+8] = *(uint4*)&hb[8];
        *(uint4*)&n1l[off] = *(uint4*)&lb[0]; *(uint4*)&n1l[off+8] = *(uint4*)&lb[8];
    }
    for (int it = tid0; it < 8192*13; it += nth) {
        int b = it / 13, f = it - b*13;
        float sc = rd[b*13 + f];
        const float* e = emb + (size_t)f*16;
        float4 e0 = *(const float4*)&e[0], e1 = *(const float4*)&e[4];
        float4 e2 = *(const float4*)&e[8], e3 = *(const float4*)&e[12];
        float vv[16] = {e0.x,e0.y,e0.z,e0.w, e1.x,e1.y,e1.z,e1.w,
                        e2.x,e2.y,e2.z,e2.w, e3.x,e3.y,e3.z,e3.w};
        unsigned short hb[16], lb[16];
        for (int j = 0; j < 16; ++j) { float v = vv[j]*sc; dsq += v*v; split2(v, hb[j], lb[j]); }
        size_t off = (size_t)b*SN0 + f*16;
        *(uint4*)&n0h[off] = *(uint4*)&hb[0]; *(uint4*)&n0h[off+8] = *(uint4*)&hb[8];
        *(uint4*)&n0l[off] = *(uint4*)&lb[0]; *(uint4*)&n0l[off+8] = *(uint4*)&lb[8];
    }
    for (int o = 32; o > 0; o >>= 1) { ssq += __shfl_down(ssq, o); dsq += __shfl_down(dsq, o); }
    __shared__ float red[8];
    int wave = threadIdx.x >> 6, lane = threadIdx.x & 63;
    if (lane == 0) { red[wave] = dsq; red[4+wave] = ssq; }
    __syncthreads();
    if (threadIdx.x == 0) {
        partial[blockIdx.x*2]   = red[0]+red[1]+red[2]+red[3];
        partial[blockIdx.x*2+1] = red[4]+red[5]+red[6]+red[7];
    }
}

__global__ __launch_bounds__(256) void finalize_kernel(
    const float* __restrict__ clf_b, const float* __restrict__ partial, float* __restrict__ out)
{
    if (blockIdx.x < 32) {
        out[blockIdx.x*256 + threadIdx.x] = clf_b[0];
        return;
    }
    float d = 0.f, s = 0.f;
    for (int i = threadIdx.x; i < EMB_BLOCKS; i += 256) { d += partial[2*i]; s += partial[2*i+1]; }
    for (int o = 32; o > 0; o >>= 1) { d += __shfl_down(d, o); s += __shfl_down(s, o); }
    __shared__ float red[8];
    int wave = threadIdx.x >> 6, lane = threadIdx.x & 63;
    if (lane == 0) { red[wave] = d; red[4+wave] = s; }
    __syncthreads();
    if (threadIdx.x == 0) {
        float dd = red[0]+red[1]+red[2]+red[3];
        float ss = red[4]+red[5]+red[6]+red[7];
        out[8192] = 1e-5f * (sqrtf(dd) + sqrtf(ss));
    }
}

// ---------------- LDS-free split-bf16 MFMA GEMM ----------------
// One wave (64 threads) per 64x64 C-tile. Fragments loaded straight from
// global ([row][k] layouts, L2-resident). 896 blocks, XCD-swizzled.
// A' = [seg1 (stride sA, k<KA) | node1 (stride SN1)]; B planes [448][Kw].
__global__ __launch_bounds__(64) void mfma_gemm(
    const unsigned short* __restrict__ a1h, const unsigned short* __restrict__ a1l, int sA, int KA,
    const unsigned short* __restrict__ a2h, const unsigned short* __restrict__ a2l,
    const unsigned short* __restrict__ bph, int Kp, int Kw,
    const float* __restrict__ vec, int relu,
    unsigned short* __restrict__ ch, unsigned short* __restrict__ cl,
    const float* __restrict__ lw, float* __restrict__ lout)
{
    int f = blockIdx.x;
    int xcd = f & 7, idx = f >> 3;          // 112 per XCD = 16 y-tiles x 7 x-tiles
    int yq = idx / 7;
    int ytile = xcd*16 + yq;
    int xtile = idx - yq*7;
    int bm = ytile*64, bn = xtile*64;
    int lane = threadIdx.x;
    int r31 = lane & 31, hh = lane >> 5;
    int khalf = hh*8;

    // per-lane row pointers (m-tile 0 rows; m-tile 1 adds 32*stride)
    const unsigned short* A1h = a1h + (size_t)(bm + r31)*sA + khalf;
    const unsigned short* A1l = a1l + (size_t)(bm + r31)*sA + khalf;
    const unsigned short* A2h = a2h + (size_t)(bm + r31)*SN1 + khalf;
    const unsigned short* A2l = a2l + (size_t)(bm + r31)*SN1 + khalf;
    const unsigned short* Bh  = bph + (size_t)(bn + r31)*Kw + khalf;
    const unsigned short* Bl  = Bh + (size_t)448*Kw;

    floatx16 acc00, acc01, acc10, acc11;
    for (int i = 0; i < 16; ++i) { acc00[i]=0.f; acc01[i]=0.f; acc10[i]=0.f; acc11[i]=0.f; }

    short8 xah0,xah1,xal0,xal1,xbh0,xbh1,xbl0,xbl1;
    short8 yah0,yah1,yal0,yal1,ybh0,ybh1,ybl0,ybl1;

    #define LOADF(P,ah0_,ah1_,al0_,al1_,bh0_,bh1_,bl0_,bl1_) do {              \
        int kb = (P);                                                          \
        if (kb < KA) {                                                         \
            ah0_ = *(const short8*)(A1h + kb);                                 \
            ah1_ = *(const short8*)(A1h + 32*sA + kb);                         \
            al0_ = *(const short8*)(A1l + kb);                                 \
            al1_ = *(const short8*)(A1l + 32*sA + kb);                         \
        } else {                                                               \
            int kc = kb - KA;                                                  \
            ah0_ = *(const short8*)(A2h + kc);                                 \
            ah1_ = *(const short8*)(A2h + 32*SN1 + kc);                        \
            al0_ = *(const short8*)(A2l + kc);                                 \
            al1_ = *(const short8*)(A2l + 32*SN1 + kc);                        \
        }                                                                      \
        bh0_ = *(const short8*)(Bh + kb);                                      \
        bh1_ = *(const short8*)(Bh + 32*Kw + kb);                              \
        bl0_ = *(const short8*)(Bl + kb);                                      \
        bl1_ = *(const short8*)(Bl + 32*Kw + kb);                              \
    } while(0)

    #define MFMAS(ah0_,ah1_,al0_,al1_,bh0_,bh1_,bl0_,bl1_) do {                \
        acc00 = __builtin_amdgcn_mfma_f32_32x32x16_bf16(ah0_, bh0_, acc00,0,0,0); \
        acc01 = __builtin_amdgcn_mfma_f32_32x32x16_bf16(ah0_, bh1_, acc01,0,0,0); \
        acc10 = __builtin_amdgcn_mfma_f32_32x32x16_bf16(ah1_, bh0_, acc10,0,0,0); \
        acc11 = __builtin_amdgcn_mfma_f32_32x32x16_bf16(ah1_, bh1_, acc11,0,0,0); \
        acc00 = __builtin_amdgcn_mfma_f32_32x32x16_bf16(ah0_, bl0_, acc00,0,0,0); \
        acc01 = __builtin_amdgcn_mfma_f32_32x32x16_bf16(ah0_, bl1_, acc01,0,0,0); \
        acc10 = __builtin_amdgcn_mfma_f32_32x32x16_bf16(ah1_, bl0_, acc10,0,0,0); \
        acc11 = __builtin_amdgcn_mfma_f32_32x32x16_bf16(ah1_, bl1_, acc11,0,0,0); \
        acc00 = __builtin_amdgcn_mfma_f32_32x32x16_bf16(al0_, bh0_, acc00,0,0,0); \
        acc01 = __builtin_amdgcn_mfma_f32_32x32x16_bf16(al0_, bh1_, acc01,0,0,0); \
        acc10 = __builtin_amdgcn_mfma_f32_32x32x16_bf16(al1_, bh0_, acc10,0,0,0); \
        acc11 = __builtin_amdgcn_mfma_f32_32x32x16_bf16(al1_, bh1_, acc11,0,0,0); \
    } while(0)

    int nk = Kp >> 4;
    LOADF(0, xah0,xah1,xal0,xal1,xbh0,xbh1,xbl0,xbl1);
    for (int s = 0; s < nk; ) {
        if (s+1 < nk) LOADF((s+1)<<4, yah0,yah1,yal0,yal1,ybh0,ybh1,ybl0,ybl1);
        MFMAS(xah0,xah1,xal0,xal1,xbh0,xbh1,xbl0,xbl1);
        ++s; if (s >= nk) break;
        if (s+1 < nk) LOADF((s+1)<<4, xah0,xah1,xal0,xal1,xbh0,xbh1,xbl0,xbl1);
        MFMAS(yah0,yah1,yal0,yal1,ybh0,ybh1,ybl0,ybl1);
        ++s;
    }
    #undef LOADF
    #undef MFMAS

    // epilogue: C/D layout col=lane&31, row=(reg&3)+8*(reg>>2)+4*(lane>>5)
    float lsum0[16], lsum1[16];
    #pragma unroll
    for (int r = 0; r < 16; ++r) { lsum0[r] = 0.f; lsum1[r] = 0.f; }
    #pragma unroll
    for (int p = 0; p < 2; ++p) {
        float* lsum = p ? lsum1 : lsum0;
        #pragma unroll
        for (int q = 0; q < 2; ++q) {
            const floatx16& ac = (p==0) ? (q==0 ? acc00 : acc01) : (q==0 ? acc10 : acc11);
            int gn = bn + q*32 + r31;
            bool ok = gn < 400;
            float vc = ok ? vec[gn] : 0.f;
            float wv = (lw && ok) ? lw[gn] : 0.f;
            #pragma unroll
            for (int r = 0; r < 16; ++r) {
                int rr = (r & 3) + 8*(r >> 2) + 4*hh;
                int gm = bm + p*32 + rr;
                float v = ac[r] + vc;
                if (relu) v = fmaxf(v, 0.f);
                if (ok) {
                    unsigned short h16, l16;
                    split2(v, h16, l16);
                    ch[(size_t)gm*SH + gn] = h16;
                    cl[(size_t)gm*SH + gn] = l16;
                }
                lsum[r] += v * wv;
            }
        }
    }
    if (lw) {
        #pragma unroll
        for (int o = 1; o < 32; o <<= 1) {
            #pragma unroll
            for (int r = 0; r < 16; ++r) {
                lsum0[r] += __shfl_xor(lsum0[r], o);
                lsum1[r] += __shfl_xor(lsum1[r], o);
            }
        }
        if (r31 == 0) {
            #pragma unroll
            for (int r = 0; r < 16; ++r) {
                int rr = (r & 3) + 8*(r >> 2) + 4*hh;
                atomicAdd(&lout[bm + rr],      lsum0[r]);
                atomicAdd(&lout[bm + 32 + rr], lsum1[r]);
            }
        }
    }
}

// ---------------- host ----------------
static inline size_t align64(size_t x) { return (x + 63) & ~(size_t)63; }

extern "C" void kernel_launch(void* const* d_in, const int* in_sizes, int n_in,
                              void* d_out, int out_size, void* d_ws, size_t ws_size,
                              hipStream_t stream)
{
    const float* raw_dense  = (const float*)d_in[0];
    const int*   raw_sparse = (const int*)d_in[1];
    const float* emb   = (const float*)d_in[2];
    const float* Pd    = (const float*)d_in[3];
    const float* Ps    = (const float*)d_in[4];
    const float* Pb    = (const float*)d_in[5];
    const float* Wc    = (const float*)d_in[6];
    const float* bc    = (const float*)d_in[7];
    const float* clf_w = (const float*)d_in[8];
    const float* clf_b = (const float*)d_in[9];
    const float* a0 = (const float*)d_in[10];
    const float* a1 = (const float*)d_in[11];
    const float* a2 = (const float*)d_in[12];
    const float* a3 = (const float*)d_in[13];
    float* out = (float*)d_out;

    char* p = (char*)d_ws;
    auto alloc = [&](size_t bytes) { char* r = p; p += align64(bytes); return r; };

    float* scal    = (float*)alloc(32*4);
    float* partial = (float*)alloc(2*EMB_BLOCKS*4);
    float* csd     = (float*)alloc(400*4);
    float* css     = (float*)alloc(400*4);
    float* csb     = (float*)alloc(400*4);
    float* cv      = (float*)alloc(4*448*4);
    float* dv      = (float*)alloc(4*448*4);
    unsigned short* w0 = (unsigned short*)alloc((size_t)2*448*640*2);
    unsigned short* w1 = (unsigned short*)alloc((size_t)2*448*832*2);
    unsigned short* w2 = (unsigned short*)alloc((size_t)2*448*832*2);
    unsigned short* w3 = (unsigned short*)alloc((size_t)2*448*832*2);
    unsigned short* v0 = (unsigned short*)alloc((size_t)2*448*416*2);
    unsigned short* v1 = (unsigned short*)alloc((size_t)2*448*416*2);
    unsigned short* v2 = (unsigned short*)alloc((size_t)2*448*416*2);
    unsigned short* v3 = (unsigned short*)alloc((size_t)2*448*416*2);
    unsigned short* n0h = (unsigned short*)alloc((size_t)8192*SN0*2);
    unsigned short* n0l = (unsigned short*)alloc((size_t)8192*SN0*2);
    unsigned short* n1h = (unsigned short*)alloc((size_t)8192*SN1*2);
    unsigned short* n1l = (unsigned short*)alloc((size_t)8192*SN1*2);
    unsigned short* hh  = (unsigned short*)alloc((size_t)8192*SH*2);
    unsigned short* hl  = (unsigned short*)alloc((size_t)8192*SH*2);
    unsigned short* nAh = (unsigned short*)alloc((size_t)8192*SH*2);
    unsigned short* nAl = (unsigned short*)alloc((size_t)8192*SH*2);
    unsigned short* nBh = (unsigned short*)alloc((size_t)8192*SH*2);
    unsigned short* nBl = (unsigned short*)alloc((size_t)8192*SH*2);

    prep1_kernel<<<5,256,0,stream>>>(Pd,Ps,Pb,a0,a1,a2,a3,scal,csd,css,csb);
    embed_kernel<<<EMB_BLOCKS,256,0,stream>>>(raw_dense, raw_sparse, emb, n0h,n0l,n1h,n1l, partial);
    finalize_kernel<<<33,256,0,stream>>>(clf_b, partial, out);
    prep2_kernel<<<dim3(7,13,8),256,0,stream>>>(Pd,Ps,Pb,Wc,scal,w0,w1,w2,w3,v0,v1,v2,v3);
    prep3_kernel<<<4,256,0,stream>>>(scal,csd,css,csb,bc,cv,dv);

    // block 0: h = relu([node0|node1] @ w0 + cv0); node2 = h @ v0 + dv0 (+logits)
    mfma_gemm<<<896,64,0,stream>>>(n0h,n0l,SN0,208, n1h,n1l, w0, 624,640, cv+0,    1, hh,hl,  nullptr,    nullptr);
    mfma_gemm<<<896,64,0,stream>>>(hh,hl,SH,400,    n1h,n1l, v0, 400,416, dv+0,    0, nAh,nAl, clf_w,      out);
    // block 1
    mfma_gemm<<<896,64,0,stream>>>(nAh,nAl,SH,400,  n1h,n1l, w1, 816,832, cv+448,  1, hh,hl,  nullptr,    nullptr);
    mfma_gemm<<<896,64,0,stream>>>(hh,hl,SH,400,    n1h,n1l, v1, 400,416, dv+448,  0, nBh,nBl, clf_w+400,  out);
    // block 2
    mfma_gemm<<<896,64,0,stream>>>(nBh,nBl,SH,400,  n1h,n1l, w2, 816,832, cv+896,  1, hh,hl,  nullptr,    nullptr);
    mfma_gemm<<<896,64,0,stream>>>(hh,hl,SH,400,    n1h,n1l, v2, 400,416, dv+896,  0, nAh,nAl, clf_w+800,  out);
    // block 3
    mfma_gemm<<<896,64,0,stream>>>(nAh,nAl,SH,400,  n1h,n1l, w3, 816,832, cv+1344, 1, hh,hl,  nullptr,    nullptr);
    mfma_gemm<<<896,64,0,stream>>>(hh,hl,SH,400,    n1h,n1l, v3, 400,416, dv+1344, 0, nBh,nBl, clf_w+1200, out);
}